// Round 1
// baseline (500.459 us; speedup 1.0000x reference)
//
#include <hip/hip_runtime.h>
#include <hip/hip_bf16.h>

// TV-L1 optical flow, B=4, C=2 frames, H=W=512, 20 iterations.
// State buffers in d_ws: gx, gy, rho_c, norm, u1, u2, p11, p12, p21, p22
// (10 channels x 4 MB = 40 MB).

#define HH 512
#define WW 512
#define BB 4
#define NUM_ITER 20

constexpr int HW = HH * WW;
constexpr int N  = BB * HW;          // 1,048,576 pixels total
constexpr float EPS = 1e-8f;

__device__ __forceinline__ void decode(int idx, int& b, int& i, int& j, int& ij) {
    b  = idx / HW;
    ij = idx - b * HW;
    i  = ij / WW;
    j  = ij - i * WW;
}

// ---------------------------------------------------------------- init ----
__global__ void k_init(const float* __restrict__ x,
                       float* __restrict__ gx, float* __restrict__ gy,
                       float* __restrict__ rho_c, float* __restrict__ nrm,
                       float* __restrict__ u1, float* __restrict__ u2,
                       float* __restrict__ p11, float* __restrict__ p12,
                       float* __restrict__ p21, float* __restrict__ p22) {
    int idx = blockIdx.x * blockDim.x + threadIdx.x;
    if (idx >= N) return;
    int b, i, j, ij; decode(idx, b, i, j, ij);

    const float* x0 = x + (size_t)b * 2 * HW;   // frame 0
    const float* x1 = x0 + HW;                  // frame 1

    // 3x3 neighborhood of frame 1, zero-padded
    float a00 = (i > 0     && j > 0     ) ? x1[ij - WW - 1] : 0.f;
    float a01 = (i > 0                  ) ? x1[ij - WW    ] : 0.f;
    float a02 = (i > 0     && j < WW - 1) ? x1[ij - WW + 1] : 0.f;
    float a10 = (             j > 0     ) ? x1[ij      - 1] : 0.f;
    float a12 = (             j < WW - 1) ? x1[ij      + 1] : 0.f;
    float a20 = (i < HH - 1 && j > 0    ) ? x1[ij + WW - 1] : 0.f;
    float a21 = (i < HH - 1             ) ? x1[ij + WW    ] : 0.f;
    float a22 = (i < HH - 1 && j < WW-1 ) ? x1[ij + WW + 1] : 0.f;

    const float c6 = 1.f / 6.f;
    float gxv = c6 * (-a00 + a02 - 2.f * a10 + 2.f * a12 - a20 + a22);
    float gyv = c6 * (-a00 - 2.f * a01 - a02 + a20 + 2.f * a21 + a22);

    gx[idx]    = gxv;
    gy[idx]    = gyv;
    rho_c[idx] = x1[ij] - x0[ij];
    nrm[idx]   = gxv * gxv + gyv * gyv + EPS;
    u1[idx] = 0.f;  u2[idx] = 0.f;
    p11[idx] = 0.f; p12[idx] = 0.f; p21[idx] = 0.f; p22[idx] = 0.f;
}

// ------------------------------------------------------------ u update ----
// u_new = v + theta * div(p_old).  Pointwise in u (in-place safe); reads
// p_old at (i, j-1..j+1) horizontally / (i-1..i+1, j) vertically via the
// trainable wx / wy taps.
__global__ void k_u(const float* __restrict__ gx, const float* __restrict__ gy,
                    const float* __restrict__ rho_c, const float* __restrict__ nrm,
                    float* __restrict__ u1, float* __restrict__ u2,
                    const float* __restrict__ p11, const float* __restrict__ p12,
                    const float* __restrict__ p21, const float* __restrict__ p22,
                    const float* __restrict__ lam_p, const float* __restrict__ theta_p,
                    const float* __restrict__ wx, const float* __restrict__ wy) {
    int idx = blockIdx.x * blockDim.x + threadIdx.x;
    if (idx >= N) return;
    int b, i, j, ij; decode(idx, b, i, j, ij);

    float lam   = lam_p[0];
    float theta = theta_p[0];
    float wx0 = wx[0], wx1 = wx[1], wx2 = wx[2];
    float wy0 = wy[0], wy1 = wy[1], wy2 = wy[2];

    float gxv = gx[idx], gyv = gy[idx];
    float u1v = u1[idx], u2v = u2[idx];
    float nv  = nrm[idx];

    float rho = rho_c[idx] + gxv * u1v + gyv * u2v;
    float th  = theta * lam * nv;

    float v1, v2;
    if (fabsf(rho) < th) {
        float d = rho / nv;
        v1 = u1v - d * gxv;
        v2 = u2v - d * gyv;
    } else {
        float sgn = (rho > 0.f) ? 1.f : ((rho < 0.f) ? -1.f : 0.f);
        float s = theta * lam * sgn;
        v1 = u1v - s * gxv;
        v2 = u2v - s * gyv;
    }

    // divergence with trainable taps, zero padding
    bool jl = (j > 0), jr = (j < WW - 1), it = (i > 0), ib = (i < HH - 1);

    float h11l = jl ? p11[idx - 1]  : 0.f;
    float h11r = jr ? p11[idx + 1]  : 0.f;
    float v12t = it ? p12[idx - WW] : 0.f;
    float v12b = ib ? p12[idx + WW] : 0.f;
    float div1 = wx0 * h11l + wx1 * p11[idx] + wx2 * h11r
               + wy0 * v12t + wy1 * p12[idx] + wy2 * v12b;

    float h21l = jl ? p21[idx - 1]  : 0.f;
    float h21r = jr ? p21[idx + 1]  : 0.f;
    float v22t = it ? p22[idx - WW] : 0.f;
    float v22b = ib ? p22[idx + WW] : 0.f;
    float div2 = wx0 * h21l + wx1 * p21[idx] + wx2 * h21r
               + wy0 * v22t + wy1 * p22[idx] + wy2 * v22b;

    u1[idx] = v1 + theta * div1;
    u2[idx] = v2 + theta * div2;
}

// ------------------------------------------------------------ p update ----
// p_new = (p_old + r*gu(u_new)) / (1 + r*(|gu_x|+|gu_y|)).  Pointwise in p
// (in-place safe); reads u_new at (i, j..j+1) and (i..i+1, j), zero padded.
__global__ void k_p(const float* __restrict__ u1, const float* __restrict__ u2,
                    float* __restrict__ p11, float* __restrict__ p12,
                    float* __restrict__ p21, float* __restrict__ p22,
                    const float* __restrict__ tau_p, const float* __restrict__ theta_p) {
    int idx = blockIdx.x * blockDim.x + threadIdx.x;
    if (idx >= N) return;
    int b, i, j, ij; decode(idx, b, i, j, ij);

    float r = tau_p[0] / theta_p[0];
    bool jr = (j < WW - 1), ib = (i < HH - 1);

    float u1c = u1[idx];
    float gu1x = (jr ? u1[idx + 1]  : 0.f) - u1c;
    float gu1y = (ib ? u1[idx + WW] : 0.f) - u1c;
    float u2c = u2[idx];
    float gu2x = (jr ? u2[idx + 1]  : 0.f) - u2c;
    float gu2y = (ib ? u2[idx + WW] : 0.f) - u2c;

    float d1 = 1.f + r * (fabsf(gu1x) + fabsf(gu1y));
    p11[idx] = (p11[idx] + r * gu1x) / d1;
    p12[idx] = (p12[idx] + r * gu1y) / d1;

    float d2 = 1.f + r * (fabsf(gu2x) + fabsf(gu2y));
    p21[idx] = (p21[idx] + r * gu2x) / d2;
    p22[idx] = (p22[idx] + r * gu2y) / d2;
}

// ------------------------------------------------------------- avgpool ----
// out[b,c,i,j] = mean over 3x3 zero-padded window of u_c, always /9.
__global__ void k_avg(const float* __restrict__ u1, const float* __restrict__ u2,
                      float* __restrict__ out) {
    int idx = blockIdx.x * blockDim.x + threadIdx.x;
    if (idx >= N) return;
    int b, i, j, ij; decode(idx, b, i, j, ij);

    int i0 = (i > 0) ? i - 1 : i,  i1 = (i < HH - 1) ? i + 1 : i;
    int j0 = (j > 0) ? j - 1 : j,  j1 = (j < WW - 1) ? j + 1 : j;

    float s1 = 0.f, s2 = 0.f;
    const float* u1b = u1 + (size_t)b * HW;
    const float* u2b = u2 + (size_t)b * HW;
    for (int ii = i0; ii <= i1; ++ii)
        for (int jj = j0; jj <= j1; ++jj) {
            s1 += u1b[ii * WW + jj];
            s2 += u2b[ii * WW + jj];
        }
    const float inv9 = 1.f / 9.f;
    float* ob = out + (size_t)b * 2 * HW;
    ob[ij]      = s1 * inv9;
    ob[HW + ij] = s2 * inv9;
}

// --------------------------------------------------------------- launch ---
extern "C" void kernel_launch(void* const* d_in, const int* in_sizes, int n_in,
                              void* d_out, int out_size, void* d_ws, size_t ws_size,
                              hipStream_t stream) {
    const float* x     = (const float*)d_in[0];
    const float* lam   = (const float*)d_in[1];
    const float* tau   = (const float*)d_in[2];
    const float* theta = (const float*)d_in[3];
    const float* wx    = (const float*)d_in[4];
    const float* wy    = (const float*)d_in[5];

    float* ws  = (float*)d_ws;
    float* gx  = ws + (size_t)0 * N;
    float* gy  = ws + (size_t)1 * N;
    float* rc  = ws + (size_t)2 * N;
    float* nm  = ws + (size_t)3 * N;
    float* u1  = ws + (size_t)4 * N;
    float* u2  = ws + (size_t)5 * N;
    float* p11 = ws + (size_t)6 * N;
    float* p12 = ws + (size_t)7 * N;
    float* p21 = ws + (size_t)8 * N;
    float* p22 = ws + (size_t)9 * N;

    dim3 block(256);
    dim3 grid((N + 255) / 256);

    k_init<<<grid, block, 0, stream>>>(x, gx, gy, rc, nm, u1, u2, p11, p12, p21, p22);
    for (int it = 0; it < NUM_ITER; ++it) {
        k_u<<<grid, block, 0, stream>>>(gx, gy, rc, nm, u1, u2,
                                        p11, p12, p21, p22, lam, theta, wx, wy);
        k_p<<<grid, block, 0, stream>>>(u1, u2, p11, p12, p21, p22, tau, theta);
    }
    k_avg<<<grid, block, 0, stream>>>(u1, u2, (float*)d_out);
}